// Round 9
// baseline (128.247 us; speedup 1.0000x reference)
//
#include <hip/hip_runtime.h>
#include <hip/hip_bf16.h>
#include <stdint.h>

// out[i][j] = dot(x[i], y[j]) / max(|x[i]|*|y[j]|, 1e-8) / 0.05
// x,y: [4096,1024] f32; out: [4096,4096] f32
#define MDIM 4096
#define NDIM 4096
#define KDIM 1024
#define TEMP_INV 20.0f

#define BM 128
#define BN 128
#define BK 64
#define NT (KDIM / BK)       // 16 K-tiles
#define ABUF_E (BM * BK)     // 8192 elems = 16 KB (A region; B same)
#define BUF_E (2 * ABUF_E)   // 32 KB per buffer; 2 buffers = 64 KB -> 2 blocks/CU

typedef __bf16 bf16x8 __attribute__((ext_vector_type(8)));
typedef float f32x4 __attribute__((ext_vector_type(4)));

typedef __attribute__((address_space(3))) void lds_void_t;
typedef __attribute__((address_space(1))) void glb_void_t;

__device__ __forceinline__ void async_copy16(const void* g, void* l) {
    __builtin_amdgcn_global_load_lds((glb_void_t*)(uintptr_t)g,
                                     (lds_void_t*)(uint32_t)(uintptr_t)l,
                                     16, 0, 0);
}

__device__ __forceinline__ unsigned short f32_to_bf16_rne(float f) {
    union { float f; uint32_t u; } v;
    v.f = f;
    uint32_t u = v.u;
    return (unsigned short)((u + 0x7FFFu + ((u >> 16) & 1u)) >> 16);
}

// Wave-per-row prep: no LDS, no __syncthreads. Block = 4 waves = 4 rows.
__global__ __launch_bounds__(256) void prep_kernel(const float* __restrict__ x,
                                                   const float* __restrict__ y,
                                                   unsigned short* __restrict__ xb,
                                                   unsigned short* __restrict__ yb,
                                                   float* __restrict__ rnx,
                                                   float* __restrict__ rny) {
    const int wv = threadIdx.x >> 6;
    const int lane = threadIdx.x & 63;
    const int row = blockIdx.x * 4 + wv;
    const float* src = blockIdx.y ? y : x;
    unsigned short* dst = blockIdx.y ? yb : xb;
    float* rn = blockIdx.y ? rny : rnx;

    const float4* s4 = (const float4*)(src + (size_t)row * KDIM);
    ushort4* d4 = (ushort4*)(dst + (size_t)row * KDIM);

    float ss = 0.0f;
#pragma unroll
    for (int it = 0; it < 4; ++it) {
        float4 v = s4[lane + it * 64];
        ss += v.x * v.x + v.y * v.y + v.z * v.z + v.w * v.w;
        ushort4 b;
        b.x = f32_to_bf16_rne(v.x);
        b.y = f32_to_bf16_rne(v.y);
        b.z = f32_to_bf16_rne(v.z);
        b.w = f32_to_bf16_rne(v.w);
        d4[lane + it * 64] = b;
    }
#pragma unroll
    for (int off = 32; off > 0; off >>= 1) ss += __shfl_down(ss, off);
    if (lane == 0) rn[row] = 1.0f / fmaxf(sqrtf(ss), 1e-8f);
}

// One K-tile (BK=64, 128x128 tile, 4 waves, wave tile 64x64, 16x16x32 MFMA).
// Stage t+1 into the other buffer first (gets the whole tile to land), then
// 16 ds_read_b128 + 32 MFMA straight-line; vmcnt(0)+barrier at tile end.
// The drain cost is the experiment's target: with 2 resident blocks/CU the
// OTHER block's MFMA covers this block's drain/stage/epilogue (m114), which
// a single barrier-locked block cannot do.
template <bool STAGE>
__device__ __forceinline__ void ktile(const __bf16* __restrict__ buf,
                                      __bf16* __restrict__ nbuf,
                                      const unsigned short* gAsrc,
                                      const unsigned short* gBsrc, int ktn,
                                      int aRow, int bRow, int cp0, int cp1,
                                      int tid, f32x4 (&acc)[4][4]) {
    if constexpr (STAGE) {
#pragma unroll
        for (int j = 0; j < 4; ++j)
            async_copy16(gAsrc + ktn + (size_t)(j * 32) * KDIM, nbuf + j * 2048 + tid * 8);
#pragma unroll
        for (int j = 0; j < 4; ++j)
            async_copy16(gBsrc + ktn + (size_t)(j * 32) * KDIM,
                         nbuf + ABUF_E + j * 2048 + tid * 8);
    }

    bf16x8 aF[4][2], bF[4][2];
#pragma unroll
    for (int mi = 0; mi < 4; ++mi) {
        aF[mi][0] = *(const bf16x8*)(buf + aRow + mi * 1024 + cp0);
        aF[mi][1] = *(const bf16x8*)(buf + aRow + mi * 1024 + cp1);
    }
#pragma unroll
    for (int ni = 0; ni < 4; ++ni) {
        bF[ni][0] = *(const bf16x8*)(buf + bRow + ni * 1024 + cp0);
        bF[ni][1] = *(const bf16x8*)(buf + bRow + ni * 1024 + cp1);
    }

    __builtin_amdgcn_s_setprio(1);
#pragma unroll
    for (int kh = 0; kh < 2; ++kh)
#pragma unroll
        for (int ni = 0; ni < 4; ++ni)
#pragma unroll
            for (int mi = 0; mi < 4; ++mi)
                acc[mi][ni] = __builtin_amdgcn_mfma_f32_16x16x32_bf16(
                    aF[mi][kh], bF[ni][kh], acc[mi][ni], 0, 0, 0);
    __builtin_amdgcn_s_setprio(0);

    asm volatile("s_waitcnt vmcnt(0)" ::: "memory");
    __builtin_amdgcn_sched_barrier(0);
    __builtin_amdgcn_s_barrier();
}

// 128x128 tile, BK=64, 256 threads / 4 waves (2M x 2N), wave tile 64x64,
// 16x16x32 MFMA (acc 4x4 f32x4 = 64 regs), 2 LDS buffers (64 KB total) ->
// 2 resident blocks/CU, 4 launched/CU (grid 1024): queued blocks drift and
// overlap each other's staging, drains, and the 64 MB store tail.
__global__ __launch_bounds__(256, 2) void gemm_cos_kernel(const unsigned short* __restrict__ Xb,
                                                          const unsigned short* __restrict__ Yb,
                                                          const float* __restrict__ rnx,
                                                          const float* __restrict__ rny,
                                                          float* __restrict__ out) {
    __shared__ __bf16 lds[2 * BUF_E];  // 64 KB

    const int tid = threadIdx.x;

    // Rect XCD swizzle: 1024 blocks = 8 XCD x 128; each XCD gets an 8bm x 16bn
    // rectangle (L2 footprint: 8 A-panels (2 MB) + 16 B-panels (4 MB) = 6 MB).
    const int lin = (int)(blockIdx.y * gridDim.x + blockIdx.x);
    const int x8 = lin & 7;
    const int ii = lin >> 3;  // 0..127 within XCD
    const int bm = (x8 >> 1) * 8 + (ii >> 4);
    const int bn = (x8 & 1) * 16 + (ii & 15);

    // Staging: thread t covers seg-row (t>>3) (0..31), chunk slot (t&7);
    // fetches global chunk (t&7)^(srow&7) so LDS slot c' holds chunk c'^(row&7).
    const int srow = tid >> 3;
    const int gch = (tid & 7) ^ (srow & 7);
    const unsigned short* gAsrc = Xb + (size_t)(bm * BM + srow) * KDIM + gch * 8;
    const unsigned short* gBsrc = Yb + (size_t)(bn * BN + srow) * KDIM + gch * 8;

    const int lane = tid & 63;
    const int wv = tid >> 6;
    const int wm = wv >> 1;   // 0..1 -> A rows wm*64..
    const int wn = wv & 1;    // 0..1 -> B rows wn*64..
    const int l15 = lane & 15;
    const int kb = lane >> 4;      // 0..3 k-block
    const int sw = lane & 7;       // swizzle xor term (row&7 of the frag row)

    // Fragment LDS element offsets: row*64 + swizzled-chunk*8.
    const int aRow = (wm * 64 + l15) * 64;             // + mi*1024 + cp
    const int bRow = ABUF_E + (wn * 64 + l15) * 64;    // + ni*1024 + cp
    const int cp0 = (kb ^ sw) * 8;                     // kh=0 chunk
    const int cp1 = ((4 + kb) ^ sw) * 8;               // kh=1 chunk

    f32x4 acc[4][4];
#pragma unroll
    for (int i = 0; i < 4; ++i)
#pragma unroll
        for (int j = 0; j < 4; ++j) acc[i][j] = (f32x4){};

    __bf16* buf0 = lds;
    __bf16* buf1 = lds + BUF_E;

    // ---- prologue: stage tile 0 -> buf0
#pragma unroll
    for (int j = 0; j < 4; ++j)
        async_copy16(gAsrc + (size_t)(j * 32) * KDIM, buf0 + j * 2048 + tid * 8);
#pragma unroll
    for (int j = 0; j < 4; ++j)
        async_copy16(gBsrc + (size_t)(j * 32) * KDIM, buf0 + ABUF_E + j * 2048 + tid * 8);
    asm volatile("s_waitcnt vmcnt(0)" ::: "memory");
    __builtin_amdgcn_sched_barrier(0);
    __builtin_amdgcn_s_barrier();

    // ---- main loop: ping-pong pairs, staging t+1 during t
#pragma unroll 1
    for (int t = 0; t < NT - 2; t += 2) {
        ktile<true>(buf0, buf1, gAsrc, gBsrc, (t + 1) * BK, aRow, bRow, cp0, cp1, tid, acc);
        ktile<true>(buf1, buf0, gAsrc, gBsrc, (t + 2) * BK, aRow, bRow, cp0, cp1, tid, acc);
    }
    // tile 14 (buf0): stage tile 15 -> buf1
    ktile<true>(buf0, buf1, gAsrc, gBsrc, 15 * BK, aRow, bRow, cp0, cp1, tid, acc);
    // tile 15 (buf1): no staging
    ktile<false>(buf1, buf0, gAsrc, gBsrc, 0, aRow, bRow, cp0, cp1, tid, acc);

    // Epilogue. C/D (16x16, m89/m91): col = lane&15, row = (lane>>4)*4 + reg.
    const int grbase = bm * BM + wm * 64 + kb * 4;
    const int gcbase = bn * BN + wn * 64 + l15;
    float sy[4];
#pragma unroll
    for (int ni = 0; ni < 4; ++ni) sy[ni] = rny[gcbase + ni * 16] * TEMP_INV;

#pragma unroll
    for (int mi = 0; mi < 4; ++mi) {
#pragma unroll
        for (int r = 0; r < 4; ++r) {
            const int grow = grbase + mi * 16 + r;
            const float rx = rnx[grow];
            float* orow = out + (size_t)grow * NDIM;
#pragma unroll
            for (int ni = 0; ni < 4; ++ni)
                orow[gcbase + ni * 16] = acc[mi][ni][r] * rx * sy[ni];
        }
    }
}

extern "C" void kernel_launch(void* const* d_in, const int* in_sizes, int n_in,
                              void* d_out, int out_size, void* d_ws, size_t ws_size,
                              hipStream_t stream) {
    const float* x = (const float*)d_in[0];
    const float* y = (const float*)d_in[1];
    float* out = (float*)d_out;

    char* ws = (char*)d_ws;
    unsigned short* Xb = (unsigned short*)ws;                              // 8 MB
    unsigned short* Yb = (unsigned short*)(ws + (size_t)MDIM * KDIM * 2);  // 8 MB
    float* rnx = (float*)(ws + (size_t)(MDIM + NDIM) * KDIM * 2);
    float* rny = rnx + MDIM;

    prep_kernel<<<dim3(MDIM / 4, 2), 256, 0, stream>>>(x, y, Xb, Yb, rnx, rny);
    gemm_cos_kernel<<<dim3(NDIM / BN, MDIM / BM), 256, 0, stream>>>(Xb, Yb, rnx, rny, out);
}